// Round 1
// baseline (370.293 us; speedup 1.0000x reference)
//
#include <hip/hip_runtime.h>
#include <stdint.h>

// MHA fused: qkv-proj (bf16 MFMA GEMM) -> causal flash attn (bf16 MFMA) -> out-proj
// B=2, S=2048, H=2048, heads=16, D=128.

using bf16x8 = __attribute__((ext_vector_type(8))) __bf16;
using f32x4  = __attribute__((ext_vector_type(4))) float;

#define S_LEN 2048
#define HID   2048
#define NHEAD 16
#define DHEAD 128
#define QSCALE 0.08838834764831845f  // 1/sqrt(128)

__device__ __forceinline__ unsigned short f2bf(float f) {
  union { float f; unsigned int u; } c; c.f = f;
  unsigned int u = c.u;
  return (unsigned short)((u + 0x7FFFu + ((u >> 16) & 1u)) >> 16);  // RNE
}

__device__ __forceinline__ void gload_lds16(const void* g, void* l) {
  __builtin_amdgcn_global_load_lds(
      (const __attribute__((address_space(1))) unsigned int*)g,
      (__attribute__((address_space(3))) unsigned int*)l, 16, 0, 0);
}

__device__ __forceinline__ f32x4 mfma16(bf16x8 a, bf16x8 b, f32x4 c) {
  return __builtin_amdgcn_mfma_f32_16x16x32_bf16(a, b, c, 0, 0, 0);
}

__global__ void cvt_bf16(const float* __restrict__ in, unsigned short* __restrict__ out, int n) {
  const int n4 = n >> 2;
  const int stride = gridDim.x * blockDim.x;
  for (int i = blockIdx.x * blockDim.x + threadIdx.x; i < n4; i += stride) {
    float4 v = reinterpret_cast<const float4*>(in)[i];
    ushort4 o;
    o.x = f2bf(v.x); o.y = f2bf(v.y); o.z = f2bf(v.z); o.w = f2bf(v.w);
    reinterpret_cast<ushort4*>(out)[i] = o;
  }
}

// C = A(M x K) * B(N x K)^T + bias.  128x128 tile, BK=64, 4 waves (2x2 of 64x64).
// EPI=0: scatter QKV epilogue (bf16).  EPI=1: fp32 row-major C.
template<int EPI>
__global__ __launch_bounds__(256) void gemm_bt(
    const unsigned short* __restrict__ A, const unsigned short* __restrict__ Bw,
    const float* __restrict__ bias, int K, int N,
    unsigned short* __restrict__ q_out, unsigned short* __restrict__ k_out,
    unsigned short* __restrict__ vt_out, float* __restrict__ c_out)
{
  __shared__ char lsA[128 * 128];   // [128 rows][64 bf16], XOR-swizzled within row
  __shared__ char lsB[128 * 128];
  const int tid = threadIdx.x;
  const int l = tid & 63, w = tid >> 6;
  const int wr = w >> 1, wc = w & 1;
  const int bm = blockIdx.x * 128, bn = blockIdx.y * 128;
  const int row16 = l & 15, kg = l >> 4;

  f32x4 acc[4][4] = {};

  for (int k0 = 0; k0 < K; k0 += 64) {
    // stage 16KB each of A,B: linear LDS dest, pre-swizzled global source (m173 pattern)
    #pragma unroll
    for (int c = 0; c < 4; ++c) {
      const int o = c * 4096 + tid * 16;
      const int r = o >> 7;
      const int cb = (o & 127) ^ ((r & 7) << 4);
      gload_lds16((const char*)A + ((size_t)(bm + r) * K + k0) * 2 + cb,
                  lsA + c * 4096 + (w << 10));
      gload_lds16((const char*)Bw + ((size_t)(bn + r) * K + k0) * 2 + cb,
                  lsB + c * 4096 + (w << 10));
    }
    __syncthreads();

    #pragma unroll
    for (int h = 0; h < 2; ++h) {
      bf16x8 af[4], bfr[4];
      #pragma unroll
      for (int i = 0; i < 4; ++i) {
        const int ra = wr * 64 + i * 16 + row16;
        af[i]  = *(const bf16x8*)(lsA + ra * 128 + ((h * 64 + kg * 16) ^ ((ra & 7) << 4)));
        const int rb = wc * 64 + i * 16 + row16;
        bfr[i] = *(const bf16x8*)(lsB + rb * 128 + ((h * 64 + kg * 16) ^ ((rb & 7) << 4)));
      }
      #pragma unroll
      for (int i = 0; i < 4; ++i)
        #pragma unroll
        for (int j = 0; j < 4; ++j)
          acc[i][j] = mfma16(af[i], bfr[j], acc[i][j]);
    }
    __syncthreads();
  }

  // C/D layout: col = lane&15, row = (lane>>4)*4 + reg  [m89]
  const int r0 = kg * 4;
  #pragma unroll
  for (int i = 0; i < 4; ++i) {
    const int row = bm + wr * 64 + i * 16 + r0;
    #pragma unroll
    for (int j = 0; j < 4; ++j) {
      const int col = bn + wc * 64 + j * 16 + row16;
      const float bv = bias[col];
      if (EPI == 1) {
        #pragma unroll
        for (int r = 0; r < 4; ++r)
          c_out[(size_t)(row + r) * N + col] = acc[i][j][r] + bv;
      } else {
        const int sec = col >> 11;           // 0=Q 1=K 2=V
        const int within = col & 2047;
        const int head = within >> 7, d = within & 127;
        #pragma unroll
        for (int r = 0; r < 4; ++r) {
          const int rr = row + r;
          const int b = rr >> 11, s = rr & 2047;
          const int bh = b * NHEAD + head;
          const float v = acc[i][j][r] + bv;
          if (sec == 0)
            q_out[((size_t)bh * S_LEN + s) * DHEAD + d] = f2bf(v * QSCALE);
          else if (sec == 1)
            k_out[((size_t)bh * S_LEN + s) * DHEAD + d] = f2bf(v);
          else  // V stored transposed per head: Vt[bh][d][s]
            vt_out[((size_t)bh * DHEAD + d) * S_LEN + s] = f2bf(v);
        }
      }
    }
  }
}

// Causal flash attention. Grid: (32 q-tiles, 32 bh). Block: 4 waves, each 16 q-rows.
__global__ __launch_bounds__(256) void attn_fwd(
    const unsigned short* __restrict__ Q, const unsigned short* __restrict__ Kk,
    const unsigned short* __restrict__ Vt, unsigned short* __restrict__ O)
{
  __shared__ char lsK[64 * 256];    // [64 kv][128 d] bf16, swizzled
  __shared__ char lsV[128 * 128];   // [128 d][64 s] bf16, swizzled
  __shared__ char lsP[4][16 * 128]; // per-wave [16 q][64 kv] bf16, swizzled
  const int tid = threadIdx.x, l = tid & 63, w = tid >> 6;
  const int row16 = l & 15, kg = l >> 4;
  const int qb = 31 - blockIdx.x;   // heavy (long-KV) blocks dispatch first
  const int bh = blockIdx.y;
  const int bidx = bh >> 4, head = bh & 15;

  const char* Qh = (const char*)(Q  + (size_t)bh * S_LEN * DHEAD);
  const char* Kh = (const char*)(Kk + (size_t)bh * S_LEN * DHEAD);
  const char* Vh = (const char*)(Vt + (size_t)bh * DHEAD * S_LEN);

  const int q0 = qb * 64 + w * 16;

  bf16x8 qf[4];
  #pragma unroll
  for (int t = 0; t < 4; ++t)
    qf[t] = *(const bf16x8*)(Qh + ((size_t)(q0 + row16) * DHEAD + t * 32 + kg * 8) * 2);

  float mrow[4], lrow[4];
  f32x4 oacc[8] = {};
  #pragma unroll
  for (int r = 0; r < 4; ++r) { mrow[r] = -1e30f; lrow[r] = 0.f; }

  for (int kt = 0; kt <= qb; ++kt) {
    #pragma unroll
    for (int c = 0; c < 4; ++c) {
      const int o = c * 4096 + tid * 16;
      const int rk = o >> 8;
      const int cbk = (o & 255) ^ ((rk & 7) << 4);
      gload_lds16(Kh + (size_t)(kt * 64 + rk) * 256 + cbk, lsK + c * 4096 + (w << 10));
      const int dv = o >> 7;
      const int cbv = (o & 127) ^ ((dv & 7) << 4);
      gload_lds16(Vh + (size_t)dv * 4096 + (size_t)kt * 128 + cbv, lsV + c * 4096 + (w << 10));
    }
    __syncthreads();

    // S = Q K^T (Q pre-scaled).  sc[j]: q rows (kg*4+r), kv col j*16+row16
    f32x4 sc[4] = {};
    #pragma unroll
    for (int j = 0; j < 4; ++j) {
      const int krow = j * 16 + row16;
      const int sw = (krow & 7) << 4;
      #pragma unroll
      for (int t = 0; t < 4; ++t) {
        bf16x8 kf = *(const bf16x8*)(lsK + krow * 256 + ((t * 64 + kg * 16) ^ sw));
        sc[j] = mfma16(qf[t], kf, sc[j]);
      }
    }

    if (kt == qb) {  // diagonal tile: causal mask (relative coords, both offset by qb*64)
      #pragma unroll
      for (int j = 0; j < 4; ++j) {
        const int colr = j * 16 + row16;
        #pragma unroll
        for (int r = 0; r < 4; ++r)
          if (colr > w * 16 + kg * 4 + r) sc[j][r] = -1e30f;
      }
    }

    // online softmax: row reduce across 16 lanes (same kg group)
    char* Pl = lsP[w];
    #pragma unroll
    for (int r = 0; r < 4; ++r) {
      float mx = fmaxf(fmaxf(sc[0][r], sc[1][r]), fmaxf(sc[2][r], sc[3][r]));
      #pragma unroll
      for (int off = 8; off; off >>= 1)
        mx = fmaxf(mx, __shfl_xor(mx, off, 64));
      const float mn = fmaxf(mrow[r], mx);
      const float al = __expf(mrow[r] - mn);
      mrow[r] = mn;
      float ps = 0.f;
      #pragma unroll
      for (int j = 0; j < 4; ++j) {
        const float p = __expf(sc[j][r] - mn);
        sc[j][r] = p;
        ps += p;
      }
      #pragma unroll
      for (int off = 8; off; off >>= 1)
        ps += __shfl_xor(ps, off, 64);
      lrow[r] = lrow[r] * al + ps;
      #pragma unroll
      for (int dt = 0; dt < 8; ++dt) oacc[dt][r] *= al;
      const int prow = kg * 4 + r;
      const int psw = (prow & 7) << 4;
      #pragma unroll
      for (int j = 0; j < 4; ++j)
        *(unsigned short*)(Pl + prow * 128 + (((j * 16 + row16) * 2) ^ psw)) = f2bf(sc[j][r]);
    }

    // O += P V : A-frag from ldsP, B-frag from ldsV (V stored d-major -> contiguous)
    #pragma unroll
    for (int ks = 0; ks < 2; ++ks) {
      bf16x8 pa = *(const bf16x8*)(Pl + row16 * 128 + ((ks * 64 + kg * 16) ^ ((row16 & 7) << 4)));
      #pragma unroll
      for (int dt = 0; dt < 8; ++dt) {
        const int drow = dt * 16 + row16;
        bf16x8 vf = *(const bf16x8*)(lsV + drow * 128 + ((ks * 64 + kg * 16) ^ ((drow & 7) << 4)));
        oacc[dt] = mfma16(pa, vf, oacc[dt]);
      }
    }
    __syncthreads();
  }

  #pragma unroll
  for (int r = 0; r < 4; ++r) {
    const float inv = 1.0f / lrow[r];
    const size_t orow = (size_t)(bidx * S_LEN + q0 + kg * 4 + r) * HID + (size_t)head * DHEAD;
    #pragma unroll
    for (int dt = 0; dt < 8; ++dt)
      O[orow + dt * 16 + row16] = f2bf(oacc[dt][r] * inv);
  }
}

extern "C" void kernel_launch(void* const* d_in, const int* in_sizes, int n_in,
                              void* d_out, int out_size, void* d_ws, size_t ws_size,
                              hipStream_t stream) {
  const float* x    = (const float*)d_in[0];
  const float* Wqkv = (const float*)d_in[1];
  const float* bqkv = (const float*)d_in[2];
  const float* Wout = (const float*)d_in[3];
  const float* bout = (const float*)d_in[4];
  float* out = (float*)d_out;

  // ws layout (bytes): Qb 16M | Kb 16M | Vt 16M | xb/Ob 16M (aliased) | Wqkvb 24M | Woutb 8M
  if (ws_size < 100663296) return;  // insufficient scratch -> clean validation fail
  char* ws = (char*)d_ws;
  unsigned short* Qb    = (unsigned short*)(ws);
  unsigned short* Kb    = (unsigned short*)(ws + 16777216);
  unsigned short* Vtb   = (unsigned short*)(ws + 2 * 16777216);
  unsigned short* xb    = (unsigned short*)(ws + 3 * 16777216);
  unsigned short* Ob    = xb;  // alias: xb dead after QKV GEMM, Ob written after
  unsigned short* Wqkvb = (unsigned short*)(ws + 4 * 16777216);
  unsigned short* Woutb = (unsigned short*)(ws + 4 * 16777216 + 25165824);

  cvt_bf16<<<2048, 256, 0, stream>>>(x,    xb,    4096 * 2048);
  cvt_bf16<<<2048, 256, 0, stream>>>(Wqkv, Wqkvb, 6144 * 2048);
  cvt_bf16<<<1024, 256, 0, stream>>>(Wout, Woutb, 2048 * 2048);

  gemm_bt<0><<<dim3(32, 48), 256, 0, stream>>>(xb, Wqkvb, bqkv, 2048, 6144,
                                               Qb, Kb, Vtb, nullptr);
  attn_fwd<<<dim3(32, 32), 256, 0, stream>>>(Qb, Kb, Vtb, Ob);
  gemm_bt<1><<<dim3(32, 16), 256, 0, stream>>>(Ob, Woutb, bout, 2048, 2048,
                                               nullptr, nullptr, nullptr, out);
}

// Round 2
// 284.316 us; speedup vs baseline: 1.3024x; 1.3024x over previous
//
#include <hip/hip_runtime.h>
#include <stdint.h>

// MHA fused: qkv-proj (bf16 MFMA GEMM) -> causal flash attn (bf16 MFMA) -> out-proj
// B=2, S=2048, H=2048, heads=16, D=128.

using bf16x8 = __attribute__((ext_vector_type(8))) __bf16;
using f32x4  = __attribute__((ext_vector_type(4))) float;

#define S_LEN 2048
#define HID   2048
#define NHEAD 16
#define DHEAD 128
// 1/sqrt(128) * log2(e): attention softmax runs in exp2 domain
#define QSCALE_L2E (0.08838834764831845f * 1.4426950408889634f)

__device__ __forceinline__ unsigned short f2bf(float f) {
  union { float f; unsigned int u; } c; c.f = f;
  unsigned int u = c.u;
  return (unsigned short)((u + 0x7FFFu + ((u >> 16) & 1u)) >> 16);  // RNE
}

__device__ __forceinline__ unsigned int pkbf(float a, float b) {
  union { __bf16 h[2]; unsigned int u; } x;
  x.h[0] = (__bf16)a; x.h[1] = (__bf16)b;
  return x.u;
}

__device__ __forceinline__ void gload_lds16(const void* g, void* l) {
  __builtin_amdgcn_global_load_lds(
      (const __attribute__((address_space(1))) unsigned int*)g,
      (__attribute__((address_space(3))) unsigned int*)l, 16, 0, 0);
}

__device__ __forceinline__ f32x4 mfma16(bf16x8 a, bf16x8 b, f32x4 c) {
  return __builtin_amdgcn_mfma_f32_16x16x32_bf16(a, b, c, 0, 0, 0);
}

__device__ __forceinline__ float hmax4(f32x4 v) {
  return fmaxf(fmaxf(v[0], v[1]), fmaxf(v[2], v[3]));
}

__global__ void cvt_bf16(const float* __restrict__ in, unsigned short* __restrict__ out, int n) {
  const int n4 = n >> 2;
  const int stride = gridDim.x * blockDim.x;
  for (int i = blockIdx.x * blockDim.x + threadIdx.x; i < n4; i += stride) {
    float4 v = reinterpret_cast<const float4*>(in)[i];
    ushort4 o;
    o.x = f2bf(v.x); o.y = f2bf(v.y); o.z = f2bf(v.z); o.w = f2bf(v.w);
    reinterpret_cast<ushort4*>(out)[i] = o;
  }
}

// C = A(M x K) * B(N x K)^T + bias.  128x128 tile, BK=64, 4 waves (2x2 of 64x64).
// EPI=0: scatter QKV epilogue (bf16).  EPI=1: fp32 row-major C.
template<int EPI>
__global__ __launch_bounds__(256) void gemm_bt(
    const unsigned short* __restrict__ A, const unsigned short* __restrict__ Bw,
    const float* __restrict__ bias, int K, int N,
    unsigned short* __restrict__ q_out, unsigned short* __restrict__ k_out,
    unsigned short* __restrict__ vt_out, float* __restrict__ c_out)
{
  __shared__ char lsA[128 * 128];   // [128 rows][64 bf16], XOR-swizzled within row
  __shared__ char lsB[128 * 128];
  const int tid = threadIdx.x;
  const int l = tid & 63, w = tid >> 6;
  const int wr = w >> 1, wc = w & 1;
  const int bm = blockIdx.x * 128, bn = blockIdx.y * 128;
  const int row16 = l & 15, kg = l >> 4;

  f32x4 acc[4][4] = {};

  for (int k0 = 0; k0 < K; k0 += 64) {
    #pragma unroll
    for (int c = 0; c < 4; ++c) {
      const int o = c * 4096 + tid * 16;
      const int r = o >> 7;
      const int cb = (o & 127) ^ ((r & 7) << 4);
      gload_lds16((const char*)A + ((size_t)(bm + r) * K + k0) * 2 + cb,
                  lsA + c * 4096 + (w << 10));
      gload_lds16((const char*)Bw + ((size_t)(bn + r) * K + k0) * 2 + cb,
                  lsB + c * 4096 + (w << 10));
    }
    __syncthreads();

    #pragma unroll
    for (int h = 0; h < 2; ++h) {
      bf16x8 af[4], bfr[4];
      #pragma unroll
      for (int i = 0; i < 4; ++i) {
        const int ra = wr * 64 + i * 16 + row16;
        af[i]  = *(const bf16x8*)(lsA + ra * 128 + ((h * 64 + kg * 16) ^ ((ra & 7) << 4)));
        const int rb = wc * 64 + i * 16 + row16;
        bfr[i] = *(const bf16x8*)(lsB + rb * 128 + ((h * 64 + kg * 16) ^ ((rb & 7) << 4)));
      }
      #pragma unroll
      for (int i = 0; i < 4; ++i)
        #pragma unroll
        for (int j = 0; j < 4; ++j)
          acc[i][j] = mfma16(af[i], bfr[j], acc[i][j]);
    }
    __syncthreads();
  }

  const int r0 = kg * 4;
  #pragma unroll
  for (int i = 0; i < 4; ++i) {
    const int row = bm + wr * 64 + i * 16 + r0;
    #pragma unroll
    for (int j = 0; j < 4; ++j) {
      const int col = bn + wc * 64 + j * 16 + row16;
      const float bv = bias[col];
      if (EPI == 1) {
        #pragma unroll
        for (int r = 0; r < 4; ++r)
          c_out[(size_t)(row + r) * N + col] = acc[i][j][r] + bv;
      } else {
        const int sec = col >> 11;           // 0=Q 1=K 2=V
        const int within = col & 2047;
        const int head = within >> 7, d = within & 127;
        #pragma unroll
        for (int r = 0; r < 4; ++r) {
          const int rr = row + r;
          const int b = rr >> 11, s = rr & 2047;
          const int bh = b * NHEAD + head;
          const float v = acc[i][j][r] + bv;
          if (sec == 0)
            q_out[((size_t)bh * S_LEN + s) * DHEAD + d] = f2bf(v * QSCALE_L2E);
          else if (sec == 1)
            k_out[((size_t)bh * S_LEN + s) * DHEAD + d] = f2bf(v);
          else  // V stored transposed per head: Vt[bh][d][s]
            vt_out[((size_t)bh * DHEAD + d) * S_LEN + s] = f2bf(v);
        }
      }
    }
  }
}

// Causal flash attention v2: swapped QK^T, 32 q-rows/wave, 2-phase dbuf pipeline.
// Grid: (16 q-tiles of 128 rows, 32 bh). Block: 4 waves.
__global__ __launch_bounds__(256, 2) void attn_fwd(
    const unsigned short* __restrict__ Q, const unsigned short* __restrict__ Kk,
    const unsigned short* __restrict__ Vt, unsigned short* __restrict__ O)
{
  __shared__ char lsK[2][64 * 256];    // dbuf [64 kv][128 d] bf16, XOR-swizzled
  __shared__ char lsV[2][128 * 128];   // dbuf [128 d][64 kv] bf16, XOR-swizzled
  __shared__ char lsP[4][32 * 128];    // per-wave [32 q][64 kv] bf16, XOR-swizzled
  const int tid = threadIdx.x, l = tid & 63, w = tid >> 6;
  const int row16 = l & 15, kg = l >> 4;
  // complementary pairing: blocks i and i+256 get qb summing to 15 -> each CU's
  // two resident blocks have equal total kv-iterations (34)
  const int qb = (blockIdx.y < 16) ? (15 - (int)blockIdx.x) : (int)blockIdx.x;
  const int bh = blockIdx.y;
  const int bidx = bh >> 4, head = bh & 15;

  const char* Qh = (const char*)(Q  + (size_t)bh * S_LEN * DHEAD);
  const char* Kh = (const char*)(Kk + (size_t)bh * S_LEN * DHEAD);
  const char* Vh = (const char*)(Vt + (size_t)bh * DHEAD * S_LEN);

  const int q0w = qb * 128 + w * 32;   // this wave's first q row

  // Q fragments (B-operand): qf[qs][t], q = q0w + qs*16 + row16, k = t*32 + kg*8
  bf16x8 qf[2][4];
  #pragma unroll
  for (int qs = 0; qs < 2; ++qs)
    #pragma unroll
    for (int t = 0; t < 4; ++t)
      qf[qs][t] = *(const bf16x8*)(Qh + ((size_t)(q0w + qs * 16 + row16) * DHEAD + t * 32 + kg * 8) * 2);

  float m[2]  = {-1e30f, -1e30f};
  float ls[2] = {0.f, 0.f};
  f32x4 oacc[2][8] = {};

  const int last = 2 * qb + 1;

#define STAGE(buf, kt_) do {                                                     \
    _Pragma("unroll")                                                            \
    for (int c = 0; c < 4; ++c) {                                                \
      const int o = c * 4096 + tid * 16;                                         \
      const int rk = o >> 8, cbk = (o & 255) ^ ((rk & 7) << 4);                  \
      gload_lds16(Kh + (size_t)((kt_) * 64 + rk) * 256 + cbk,                    \
                  lsK[buf] + c * 4096 + (w << 10));                              \
      const int dv = o >> 7, cbv = (o & 127) ^ ((dv & 7) << 4);                  \
      gload_lds16(Vh + (size_t)dv * 4096 + (size_t)(kt_) * 128 + cbv,            \
                  lsV[buf] + c * 4096 + (w << 10));                              \
    } } while (0)

  STAGE(0, 0);
  __syncthreads();

  int cur = 0;
  for (int kt = 0; ; ++kt) {
    if (kt < last) STAGE(cur ^ 1, kt + 1);   // prefetch next tile; hides under compute

    // waves whose entire 32 q-rows are above this kv tile skip compute
    if (kt * 64 <= q0w + 31) {
      const char* Kc = lsK[cur];
      const char* Vc = lsV[cur];
      char* Pl = lsP[w];

      // ---- S^T = K Q^T : sc[j][qs] holds S[kv = kt*64+j*16+kg*4+r][q = q0w+qs*16+row16]
      f32x4 sc[4][2] = {};
      #pragma unroll
      for (int j = 0; j < 4; ++j) {
        const int krow = j * 16 + row16;
        const int sw = (krow & 7) << 4;
        bf16x8 kf[4];
        #pragma unroll
        for (int t = 0; t < 4; ++t)
          kf[t] = *(const bf16x8*)(Kc + krow * 256 + ((t * 64 + kg * 16) ^ sw));
        #pragma unroll
        for (int t = 0; t < 4; ++t) {
          sc[j][0] = mfma16(kf[t], qf[0][t], sc[j][0]);
          sc[j][1] = mfma16(kf[t], qf[1][t], sc[j][1]);
        }
      }

      // ---- causal mask (only the last two tiles of the block touch the diagonal)
      if (kt >= 2 * qb) {
        #pragma unroll
        for (int j = 0; j < 4; ++j) {
          const int kvb = kt * 64 + j * 16 + kg * 4;
          #pragma unroll
          for (int qs = 0; qs < 2; ++qs) {
            const int qq = q0w + qs * 16 + row16;
            #pragma unroll
            for (int r = 0; r < 4; ++r)
              if (kvb + r > qq) sc[j][qs][r] = -1e30f;
          }
        }
      }

      // ---- online softmax (exp2 domain), defer-max (THR=8)
      float pm[2], al[2] = {1.f, 1.f};
      #pragma unroll
      for (int qs = 0; qs < 2; ++qs) {
        float mx = fmaxf(fmaxf(hmax4(sc[0][qs]), hmax4(sc[1][qs])),
                         fmaxf(hmax4(sc[2][qs]), hmax4(sc[3][qs])));
        mx = fmaxf(mx, __shfl_xor(mx, 16, 64));
        mx = fmaxf(mx, __shfl_xor(mx, 32, 64));
        pm[qs] = mx;
      }
      const bool need = (pm[0] > m[0] + 8.f) || (pm[1] > m[1] + 8.f);
      if (__any(need)) {
        const float n0 = fmaxf(m[0], pm[0]), n1 = fmaxf(m[1], pm[1]);
        al[0] = exp2f(m[0] - n0); al[1] = exp2f(m[1] - n1);
        m[0] = n0; m[1] = n1;
        float aq[2][4];
        #pragma unroll
        for (int qs2 = 0; qs2 < 2; ++qs2)
          #pragma unroll
          for (int r = 0; r < 4; ++r)
            aq[qs2][r] = __shfl(al[qs2], kg * 4 + r, 64);
        #pragma unroll
        for (int qs2 = 0; qs2 < 2; ++qs2)
          #pragma unroll
          for (int dt = 0; dt < 8; ++dt)
            #pragma unroll
            for (int r = 0; r < 4; ++r)
              oacc[qs2][dt][r] *= aq[qs2][r];
      }

      // ---- P = exp2(S - m), write to per-wave LDS (bf16, swizzled), row-sum
      #pragma unroll
      for (int qs = 0; qs < 2; ++qs) {
        const int q = qs * 16 + row16;
        const int psw = (q & 7) << 4;
        float ps = 0.f;
        #pragma unroll
        for (int j = 0; j < 4; ++j) {
          const float p0 = exp2f(sc[j][qs][0] - m[qs]);
          const float p1 = exp2f(sc[j][qs][1] - m[qs]);
          const float p2 = exp2f(sc[j][qs][2] - m[qs]);
          const float p3 = exp2f(sc[j][qs][3] - m[qs]);
          ps += (p0 + p1) + (p2 + p3);
          uint2 pw; pw.x = pkbf(p0, p1); pw.y = pkbf(p2, p3);
          *(uint2*)(Pl + q * 128 + ((j * 32 + kg * 8) ^ psw)) = pw;
        }
        ps += __shfl_xor(ps, 16, 64);
        ps += __shfl_xor(ps, 32, 64);
        ls[qs] = ls[qs] * al[qs] + ps;
      }

      // ---- O += P V  (A = P rows q, B = Vt rows d)
      bf16x8 pa[2][2];
      #pragma unroll
      for (int qs2 = 0; qs2 < 2; ++qs2) {
        const int q = qs2 * 16 + row16;
        #pragma unroll
        for (int ks = 0; ks < 2; ++ks)
          pa[qs2][ks] = *(const bf16x8*)(Pl + q * 128 + ((ks * 64 + kg * 16) ^ ((q & 7) << 4)));
      }
      #pragma unroll
      for (int dt = 0; dt < 8; ++dt) {
        const int drow = dt * 16 + row16;
        const int vsw = (drow & 7) << 4;
        bf16x8 v0 = *(const bf16x8*)(Vc + drow * 128 + ((kg * 16) ^ vsw));
        bf16x8 v1 = *(const bf16x8*)(Vc + drow * 128 + ((64 + kg * 16) ^ vsw));
        oacc[0][dt] = mfma16(pa[0][0], v0, oacc[0][dt]);
        oacc[0][dt] = mfma16(pa[0][1], v1, oacc[0][dt]);
        oacc[1][dt] = mfma16(pa[1][0], v0, oacc[1][dt]);
        oacc[1][dt] = mfma16(pa[1][1], v1, oacc[1][dt]);
      }
    }

    __syncthreads();   // drains prefetch (vmcnt) + joins waves before buffer swap
    if (kt == last) break;
    cur ^= 1;
  }
#undef STAGE

  // ---- epilogue: normalize rows, write O[b*S + q][head*128 + d] bf16
  #pragma unroll
  for (int qs2 = 0; qs2 < 2; ++qs2) {
    #pragma unroll
    for (int r = 0; r < 4; ++r) {
      const float lr = __shfl(ls[qs2], kg * 4 + r, 64);
      const float inv = 1.0f / lr;
      const int q = q0w + qs2 * 16 + kg * 4 + r;
      const size_t orow = (size_t)(bidx * S_LEN + q) * HID + (size_t)head * DHEAD;
      #pragma unroll
      for (int dt = 0; dt < 8; ++dt)
        O[orow + dt * 16 + row16] = f2bf(oacc[qs2][dt][r] * inv);
    }
  }
}

extern "C" void kernel_launch(void* const* d_in, const int* in_sizes, int n_in,
                              void* d_out, int out_size, void* d_ws, size_t ws_size,
                              hipStream_t stream) {
  const float* x    = (const float*)d_in[0];
  const float* Wqkv = (const float*)d_in[1];
  const float* bqkv = (const float*)d_in[2];
  const float* Wout = (const float*)d_in[3];
  const float* bout = (const float*)d_in[4];
  float* out = (float*)d_out;

  if (ws_size < 100663296) return;  // insufficient scratch -> clean validation fail
  char* ws = (char*)d_ws;
  unsigned short* Qb    = (unsigned short*)(ws);
  unsigned short* Kb    = (unsigned short*)(ws + 16777216);
  unsigned short* Vtb   = (unsigned short*)(ws + 2 * 16777216);
  unsigned short* xb    = (unsigned short*)(ws + 3 * 16777216);
  unsigned short* Ob    = xb;  // alias: xb dead after QKV GEMM, Ob written after
  unsigned short* Wqkvb = (unsigned short*)(ws + 4 * 16777216);
  unsigned short* Woutb = (unsigned short*)(ws + 4 * 16777216 + 25165824);

  cvt_bf16<<<2048, 256, 0, stream>>>(x,    xb,    4096 * 2048);
  cvt_bf16<<<2048, 256, 0, stream>>>(Wqkv, Wqkvb, 6144 * 2048);
  cvt_bf16<<<1024, 256, 0, stream>>>(Wout, Woutb, 2048 * 2048);

  gemm_bt<0><<<dim3(32, 48), 256, 0, stream>>>(xb, Wqkvb, bqkv, 2048, 6144,
                                               Qb, Kb, Vtb, nullptr);
  attn_fwd<<<dim3(16, 32), 256, 0, stream>>>(Qb, Kb, Vtb, Ob);
  gemm_bt<1><<<dim3(32, 16), 256, 0, stream>>>(Ob, Woutb, bout, 2048, 2048,
                                               nullptr, nullptr, nullptr, out);
}